// Round 9
// baseline (423.573 us; speedup 1.0000x reference)
//
#include <hip/hip_runtime.h>
#include <stdint.h>

#define C_DIM 1024
#define HW    4096
#define KPAD  1056
#define KIN   1049
#define NPIX  32768   // 8*64*64
#define NCHUNK 16     // corr channel chunks (64 ch each)

typedef __bf16 bf16x8 __attribute__((ext_vector_type(8)));
typedef float  f32x4  __attribute__((ext_vector_type(4)));
typedef float  f32x2  __attribute__((ext_vector_type(2)));
typedef unsigned short u16x8 __attribute__((ext_vector_type(8)));

typedef const __attribute__((address_space(1))) void* gas_t;
typedef __attribute__((address_space(3))) void* las_t;

__device__ __forceinline__ unsigned short f2bf(float f) {
  unsigned u = __float_as_uint(f);
  unsigned r = u + 0x7FFFu + ((u >> 16) & 1u);
  return (unsigned short)(r >> 16);
}

// ---------------------------------------------------------------------------
// K1: pack conv_w [1024][1049] fp32 -> wb [1024][1056] bf16 (zero pad tail)
// ---------------------------------------------------------------------------
__global__ __launch_bounds__(256) void prep_w(const float* __restrict__ cw,
                                              unsigned short* __restrict__ wb) {
  int o = blockIdx.x;
  for (int k = threadIdx.x; k < KPAD; k += 256) {
    float v = (k < KIN) ? cw[(size_t)o * KIN + k] : 0.0f;
    wb[(size_t)o * KPAD + k] = f2bf(v);
  }
}

// ---------------------------------------------------------------------------
// K2: feature fp32 -> xb rows cols 0..1023 + inv_norm (unchanged, validated)
// ---------------------------------------------------------------------------
__global__ __launch_bounds__(256) void pack_norm(const float* __restrict__ feat,
                                                 unsigned short* __restrict__ xb,
                                                 float* __restrict__ inv_norm,
                                                 int p_base) {
  __shared__ float tile[64][65];
  __shared__ float red[4][64];
  int t   = threadIdx.x;
  int p0l = blockIdx.x * 64;
  int p0g = p_base + p0l;
  int b   = p0g >> 12;
  int hw0 = p0g & 4095;
  int pl = t & 63;
  int q  = t >> 6;
  const float* fb = feat + (size_t)b * C_DIM * HW + hw0;
  float sumsq = 0.0f;
  for (int cc = 0; cc < 16; ++cc) {
#pragma unroll
    for (int i = 0; i < 16; ++i) {
      int cl = q + 4 * i;
      float v = fb[(size_t)(cc * 64 + cl) * HW + pl];
      sumsq += v * v;
      tile[cl][pl] = v;
    }
    __syncthreads();
#pragma unroll
    for (int r = 0; r < 2; ++r) {
      int id = t + r * 256;
      int pr = id >> 3;
      int c8 = id & 7;
      u16x8 hv;
#pragma unroll
      for (int e = 0; e < 8; ++e) hv[e] = f2bf(tile[c8 * 8 + e][pr]);
      size_t row = (size_t)(p0l + pr) * KPAD + cc * 64 + c8 * 8;
      *reinterpret_cast<u16x8*>(xb + row) = hv;
    }
    __syncthreads();
  }
  red[q][pl] = sumsq;
  __syncthreads();
  if (t < 64) {
    float s = red[0][t] + red[1][t] + red[2][t] + red[3][t];
    inv_norm[p0g + t] = 1.0f / fmaxf(sqrtf(s), 1e-12f);
  }
}

// ---------------------------------------------------------------------------
// K3 v4: corr partials, 3-deep counted-vmcnt pipeline (T4).
//   3 buffers x 2 channels; iter it: issue stage(it+2), compute buf it%3,
//   s_waitcnt vmcnt(4) (buf it+1 landed, it+2 still in flight), raw barrier.
// ---------------------------------------------------------------------------
__global__ __launch_bounds__(256) void corr_part(const float* __restrict__ feat,
                                                 float* __restrict__ part) {
  __shared__ float lbuf[3][2][1288];   // [buf][ch][4 guard | 20x64 | 4 guard]
  int t = threadIdx.x;
  int bid = blockIdx.x;
  int chunk = bid & 15;
  int strip = (bid >> 4) & 3;
  int b     = bid >> 6;
  int h0 = strip * 16;
  int hr = t >> 4;          // row within strip (0..15)
  int w0 = (t & 15) * 4;    // 4 pixels w0..w0+3
  int wid = t >> 6;
  int lane = t & 63;

  const float* fb = feat + (size_t)b * C_DIM * HW;
  int rA = t >> 4;
  int cA = (t & 15) * 4;
  int hA = min(max(h0 - 2 + rA, 0), 63);
  int rB = 16 + wid;
  int cB = lane;
  int hB = min(max(h0 - 2 + rB, 0), 63);
  const float* srcA = fb + hA * 64 + cA;
  const float* srcB = fb + hB * 64 + cB;
  int c0 = chunk * 64;

  float acc[4][25];
#pragma unroll
  for (int j = 0; j < 4; ++j)
#pragma unroll
    for (int k = 0; k < 25; ++k) acc[j][k] = 0.0f;

  // stage channels (c0+c, c0+c+1) into lbuf[bsel] : 4 gl_lds issues
  auto stage2 = [&](int bsel, int c) {
#pragma unroll
    for (int cs = 0; cs < 2; ++cs) {
      float* dst = &lbuf[bsel][cs][4];
      size_t coff = (size_t)(c0 + c + cs) * HW;
      __builtin_amdgcn_global_load_lds((gas_t)(srcA + coff),
                                       (las_t)(dst + wid * 256), 16, 0, 0);
      __builtin_amdgcn_global_load_lds((gas_t)(srcB + coff),
                                       (las_t)(dst + 1024 + wid * 64), 4, 0, 0);
    }
  };

  stage2(0, 0);
  stage2(1, 2);
  asm volatile("s_waitcnt vmcnt(4)" ::: "memory");   // buf0 landed
  __builtin_amdgcn_sched_barrier(0);
  __builtin_amdgcn_s_barrier();

  for (int it = 0; it < 32; ++it) {
    if (it + 2 < 32) stage2((it + 2) % 3, 2 * (it + 2));
#pragma unroll
    for (int cc = 0; cc < 2; ++cc) {
      const float* tile = &lbuf[it % 3][cc][4];
      const float* rp2 = tile + (hr + 2) * 64 + w0;
      f32x4 ctr4 = *reinterpret_cast<const f32x4*>(rp2);
#pragma unroll
      for (int r5 = 0; r5 < 5; ++r5) {
        const float* rp = tile + (hr + r5) * 64 + w0;
        f32x2 eL = *reinterpret_cast<const f32x2*>(rp - 2);
        f32x4 cc4 = *reinterpret_cast<const f32x4*>(rp);
        f32x2 eR = *reinterpret_cast<const f32x2*>(rp + 4);
        float win[8] = {eL[0], eL[1], cc4[0], cc4[1], cc4[2], cc4[3], eR[0], eR[1]};
#pragma unroll
        for (int j = 0; j < 4; ++j)
#pragma unroll
          for (int dcv = 0; dcv < 5; ++dcv)
            acc[j][dcv * 5 + r5] += win[j + dcv] * ctr4[j];
      }
    }
    // buf it+1 must be landed before next iter; keep buf it+2's 4 loads flying
    if (it < 30) asm volatile("s_waitcnt vmcnt(4)" ::: "memory");
    else         asm volatile("s_waitcnt vmcnt(0)" ::: "memory");
    __builtin_amdgcn_sched_barrier(0);
    __builtin_amdgcn_s_barrier();
  }

  int p0 = b * 4096 + (h0 + hr) * 64 + w0;
#pragma unroll
  for (int jj = 0; jj < 25; ++jj) {
    f32x4 v = {acc[0][jj], acc[1][jj], acc[2][jj], acc[3][jj]};
    *reinterpret_cast<f32x4*>(&part[(size_t)(chunk * 25 + jj) * NPIX + p0]) = v;
  }
}

// ---------------------------------------------------------------------------
// K4: reduce 16 chunks, scale by inv[p]*inv[p+d], write x cols 1024..1055
// ---------------------------------------------------------------------------
__global__ __launch_bounds__(256) void corr_reduce(const float* __restrict__ part,
                                                   const float* __restrict__ inv_norm,
                                                   unsigned short* __restrict__ xb) {
  int pl = blockIdx.x * 256 + threadIdx.x;
  int w = pl & 63, h = (pl >> 6) & 63, b = pl >> 12;
  float inv_c = inv_norm[pl];
  float vals[32];
#pragma unroll
  for (int j = 0; j < 32; ++j) {
    float v = 0.0f;
    if (j < 25) {
      int dc = j / 5 - 2, dr = j % 5 - 2;
      int hh = h + dr, ww = w + dc;
      if (hh >= 0 && hh < 64 && ww >= 0 && ww < 64) {
        float s = 0.0f;
#pragma unroll
        for (int c = 0; c < NCHUNK; ++c)
          s += part[(size_t)(c * 25 + j) * NPIX + pl];
        v = s * inv_c * inv_norm[(b << 12) + (hh << 6) + ww];
      }
    }
    vals[j] = v;
  }
  unsigned short* xp = xb + (size_t)pl * KPAD + 1024;
#pragma unroll
  for (int g = 0; g < 4; ++g) {
    u16x8 pk;
#pragma unroll
    for (int e = 0; e < 8; ++e) pk[e] = f2bf(vals[g * 8 + e]);
    *reinterpret_cast<u16x8*>(xp + g * 8) = pk;
  }
}

// ---------------------------------------------------------------------------
// K5: GEMM, 3-deep counted-vmcnt K-loop (T4).
//     Iter kt: issue stage(kt+2) -> 16 MFMA from buf kt%3 ->
//     s_waitcnt vmcnt(4) (tile kt+1 landed; kt+2's 4 loads span the barrier)
//     -> raw s_barrier. BM=BN=128, BK=32, 4 waves, 16x16x32 MFMA,
//     source-side XOR swizzle, XCD-clustered mapping.
// ---------------------------------------------------------------------------
__device__ __forceinline__ void stage_tile(const unsigned short* __restrict__ g,
                                           unsigned short* s, int t) {
#pragma unroll
  for (int r = 0; r < 2; ++r) {
    int idx = t + r * 256;
    int row = idx >> 2;
    int q = (idx & 3) ^ ((row >> 1) & 3);
    const unsigned short* gp = g + (size_t)row * KPAD + q * 8;
    unsigned short* sp = s + (t >> 6) * 512 + r * 2048;
    __builtin_amdgcn_global_load_lds((gas_t)gp, (las_t)sp, 16, 0, 0);
  }
}

__global__ __launch_bounds__(256, 2) void gemm_kernel(
    const unsigned short* __restrict__ xb, const unsigned short* __restrict__ wb,
    const float* __restrict__ bias, float* __restrict__ out,
    int p_base, int np) {
  __shared__ __align__(16) unsigned short sA[3][4096];
  __shared__ __align__(16) unsigned short sB[3][4096];
  int t = threadIdx.x;
  int lane = t & 63;
  int wid = t >> 6;
  int wm = wid >> 1, wn = wid & 1;
  int l15 = lane & 15, l4 = lane >> 4;
  int bid = blockIdx.x;
  int xcd = bid & 7;
  int j = bid >> 3;
  int o0 = (j & 7) * 128;
  int panel = xcd * (np >> 3) + (j >> 3);
  int p0l = panel * 128;

  f32x4 acc[4][4];
#pragma unroll
  for (int m = 0; m < 4; ++m)
#pragma unroll
    for (int n = 0; n < 4; ++n)
#pragma unroll
      for (int i = 0; i < 4; ++i) acc[m][n][i] = 0.0f;

  const unsigned short* A = wb + (size_t)o0 * KPAD;
  const unsigned short* B = xb + (size_t)p0l * KPAD;

  const int NKT = KPAD / 32;   // 33
  stage_tile(A, sA[0], t);
  stage_tile(B, sB[0], t);
  stage_tile(A + 32, sA[1], t);
  stage_tile(B + 32, sB[1], t);
  asm volatile("s_waitcnt vmcnt(4)" ::: "memory");   // tile 0 landed
  __builtin_amdgcn_sched_barrier(0);
  __builtin_amdgcn_s_barrier();

  for (int kt = 0; kt < NKT; ++kt) {
    if (kt + 2 < NKT) {
      stage_tile(A + (kt + 2) * 32, sA[(kt + 2) % 3], t);
      stage_tile(B + (kt + 2) * 32, sB[(kt + 2) % 3], t);
    }
    const unsigned short* cA = sA[kt % 3];
    const unsigned short* cB = sB[kt % 3];
    bf16x8 bf[4];
#pragma unroll
    for (int n = 0; n < 4; ++n) {
      int rr = wn * 64 + n * 16 + l15;
      int off = rr * 32 + ((l4 ^ ((rr >> 1) & 3)) * 8);
      bf[n] = *reinterpret_cast<const bf16x8*>(&cB[off]);
    }
#pragma unroll
    for (int m = 0; m < 4; ++m) {
      int ra = wm * 64 + m * 16 + l15;
      int off = ra * 32 + ((l4 ^ ((ra >> 1) & 3)) * 8);
      bf16x8 af = *reinterpret_cast<const bf16x8*>(&cA[off]);
#pragma unroll
      for (int n = 0; n < 4; ++n)
        acc[m][n] = __builtin_amdgcn_mfma_f32_16x16x32_bf16(af, bf[n], acc[m][n], 0, 0, 0);
    }
    if (kt < NKT - 2) asm volatile("s_waitcnt vmcnt(4)" ::: "memory");
    else              asm volatile("s_waitcnt vmcnt(0)" ::: "memory");
    __builtin_amdgcn_sched_barrier(0);
    __builtin_amdgcn_s_barrier();
  }

#pragma unroll
  for (int m = 0; m < 4; ++m) {
    int ob = o0 + wm * 64 + m * 16 + l4 * 4;
    float b0 = bias[ob], b1 = bias[ob + 1], b2 = bias[ob + 2], b3 = bias[ob + 3];
#pragma unroll
    for (int n = 0; n < 4; ++n) {
      int pg = p_base + p0l + wn * 64 + n * 16 + l15;
      int bb = pg >> 12, hw = pg & 4095;
      float* op = out + ((size_t)bb << 22) + hw;
      op[(size_t)(ob + 0) << 12] = fmaxf(acc[m][n][0] + b0, 0.0f);
      op[(size_t)(ob + 1) << 12] = fmaxf(acc[m][n][1] + b1, 0.0f);
      op[(size_t)(ob + 2) << 12] = fmaxf(acc[m][n][2] + b2, 0.0f);
      op[(size_t)(ob + 3) << 12] = fmaxf(acc[m][n][3] + b3, 0.0f);
    }
  }
}

// ---------------------------------------------------------------------------
extern "C" void kernel_launch(void* const* d_in, const int* in_sizes, int n_in,
                              void* d_out, int out_size, void* d_ws, size_t ws_size,
                              hipStream_t stream) {
  const float* feat = (const float*)d_in[0];
  const float* cw   = (const float*)d_in[1];
  const float* cb   = (const float*)d_in[2];
  float* out = (float*)d_out;

  // single pass: xb 69.2MB + wb 2.2MB + inv 0.13MB + part 52.4MB = 124MB < 512MiB
  char* ws = (char*)d_ws;
  size_t SZ_X = (size_t)NPIX * KPAD * 2;
  size_t SZ_W = (size_t)1024 * KPAD * 2;
  unsigned short* xb = (unsigned short*)(ws);
  unsigned short* wb = (unsigned short*)(ws + SZ_X);
  float* inv_norm    = (float*)(ws + SZ_X + SZ_W);
  float* part        = (float*)(ws + SZ_X + SZ_W + (size_t)NPIX * 4);

  prep_w<<<1024, 256, 0, stream>>>(cw, wb);
  pack_norm<<<512, 256, 0, stream>>>(feat, xb, inv_norm, 0);
  corr_part<<<512, 256, 0, stream>>>(feat, part);
  corr_reduce<<<128, 256, 0, stream>>>(part, inv_norm, xb);
  gemm_kernel<<<2048, 256, 0, stream>>>(xb, wb, cb, out, 0, 256);
}

// Round 10
// 411.926 us; speedup vs baseline: 1.0283x; 1.0283x over previous
//
#include <hip/hip_runtime.h>
#include <stdint.h>

#define C_DIM 1024
#define HW    4096
#define KPAD  1056
#define KIN   1049
#define NPIX  32768   // 8*64*64
#define NCHUNK 16     // corr channel chunks (64 ch each)

typedef __bf16 bf16x8 __attribute__((ext_vector_type(8)));
typedef float  f32x4  __attribute__((ext_vector_type(4)));
typedef float  f32x2  __attribute__((ext_vector_type(2)));
typedef unsigned short u16x8 __attribute__((ext_vector_type(8)));

typedef const __attribute__((address_space(1))) void* gas_t;
typedef __attribute__((address_space(3))) void* las_t;

__device__ __forceinline__ unsigned short f2bf(float f) {
  unsigned u = __float_as_uint(f);
  unsigned r = u + 0x7FFFu + ((u >> 16) & 1u);
  return (unsigned short)(r >> 16);
}

// ---------------------------------------------------------------------------
// K1: pack conv_w [1024][1049] fp32 -> wb [1024][1056] bf16 (zero pad tail)
// ---------------------------------------------------------------------------
__global__ __launch_bounds__(256) void prep_w(const float* __restrict__ cw,
                                              unsigned short* __restrict__ wb) {
  int o = blockIdx.x;
  for (int k = threadIdx.x; k < KPAD; k += 256) {
    float v = (k < KIN) ? cw[(size_t)o * KIN + k] : 0.0f;
    wb[(size_t)o * KPAD + k] = f2bf(v);
  }
}

// ---------------------------------------------------------------------------
// K2: feature fp32 -> xb rows cols 0..1023 + inv_norm (unchanged, validated)
// ---------------------------------------------------------------------------
__global__ __launch_bounds__(256) void pack_norm(const float* __restrict__ feat,
                                                 unsigned short* __restrict__ xb,
                                                 float* __restrict__ inv_norm,
                                                 int p_base) {
  __shared__ float tile[64][65];
  __shared__ float red[4][64];
  int t   = threadIdx.x;
  int p0l = blockIdx.x * 64;
  int p0g = p_base + p0l;
  int b   = p0g >> 12;
  int hw0 = p0g & 4095;
  int pl = t & 63;
  int q  = t >> 6;
  const float* fb = feat + (size_t)b * C_DIM * HW + hw0;
  float sumsq = 0.0f;
  for (int cc = 0; cc < 16; ++cc) {
#pragma unroll
    for (int i = 0; i < 16; ++i) {
      int cl = q + 4 * i;
      float v = fb[(size_t)(cc * 64 + cl) * HW + pl];
      sumsq += v * v;
      tile[cl][pl] = v;
    }
    __syncthreads();
#pragma unroll
    for (int r = 0; r < 2; ++r) {
      int id = t + r * 256;
      int pr = id >> 3;
      int c8 = id & 7;
      u16x8 hv;
#pragma unroll
      for (int e = 0; e < 8; ++e) hv[e] = f2bf(tile[c8 * 8 + e][pr]);
      size_t row = (size_t)(p0l + pr) * KPAD + cc * 64 + c8 * 8;
      *reinterpret_cast<u16x8*>(xb + row) = hv;
    }
    __syncthreads();
  }
  red[q][pl] = sumsq;
  __syncthreads();
  if (t < 64) {
    float s = red[0][t] + red[1][t] + red[2][t] + red[3][t];
    inv_norm[p0g + t] = 1.0f / fmaxf(sqrtf(s), 1e-12f);
  }
}

// ---------------------------------------------------------------------------
// K3 v4: corr partials, 3-deep counted-vmcnt pipeline (validated -8us).
// ---------------------------------------------------------------------------
__global__ __launch_bounds__(256) void corr_part(const float* __restrict__ feat,
                                                 float* __restrict__ part) {
  __shared__ float lbuf[3][2][1288];   // [buf][ch][4 guard | 20x64 | 4 guard]
  int t = threadIdx.x;
  int bid = blockIdx.x;
  int chunk = bid & 15;
  int strip = (bid >> 4) & 3;
  int b     = bid >> 6;
  int h0 = strip * 16;
  int hr = t >> 4;          // row within strip (0..15)
  int w0 = (t & 15) * 4;    // 4 pixels w0..w0+3
  int wid = t >> 6;
  int lane = t & 63;

  const float* fb = feat + (size_t)b * C_DIM * HW;
  int rA = t >> 4;
  int cA = (t & 15) * 4;
  int hA = min(max(h0 - 2 + rA, 0), 63);
  int rB = 16 + wid;
  int cB = lane;
  int hB = min(max(h0 - 2 + rB, 0), 63);
  const float* srcA = fb + hA * 64 + cA;
  const float* srcB = fb + hB * 64 + cB;
  int c0 = chunk * 64;

  float acc[4][25];
#pragma unroll
  for (int j = 0; j < 4; ++j)
#pragma unroll
    for (int k = 0; k < 25; ++k) acc[j][k] = 0.0f;

  auto stage2 = [&](int bsel, int c) {
#pragma unroll
    for (int cs = 0; cs < 2; ++cs) {
      float* dst = &lbuf[bsel][cs][4];
      size_t coff = (size_t)(c0 + c + cs) * HW;
      __builtin_amdgcn_global_load_lds((gas_t)(srcA + coff),
                                       (las_t)(dst + wid * 256), 16, 0, 0);
      __builtin_amdgcn_global_load_lds((gas_t)(srcB + coff),
                                       (las_t)(dst + 1024 + wid * 64), 4, 0, 0);
    }
  };

  stage2(0, 0);
  stage2(1, 2);
  asm volatile("s_waitcnt vmcnt(4)" ::: "memory");   // buf0 landed
  __builtin_amdgcn_sched_barrier(0);
  __builtin_amdgcn_s_barrier();

  for (int it = 0; it < 32; ++it) {
    if (it + 2 < 32) stage2((it + 2) % 3, 2 * (it + 2));
#pragma unroll
    for (int cc = 0; cc < 2; ++cc) {
      const float* tile = &lbuf[it % 3][cc][4];
      const float* rp2 = tile + (hr + 2) * 64 + w0;
      f32x4 ctr4 = *reinterpret_cast<const f32x4*>(rp2);
#pragma unroll
      for (int r5 = 0; r5 < 5; ++r5) {
        const float* rp = tile + (hr + r5) * 64 + w0;
        f32x2 eL = *reinterpret_cast<const f32x2*>(rp - 2);
        f32x4 cc4 = *reinterpret_cast<const f32x4*>(rp);
        f32x2 eR = *reinterpret_cast<const f32x2*>(rp + 4);
        float win[8] = {eL[0], eL[1], cc4[0], cc4[1], cc4[2], cc4[3], eR[0], eR[1]};
#pragma unroll
        for (int j = 0; j < 4; ++j)
#pragma unroll
          for (int dcv = 0; dcv < 5; ++dcv)
            acc[j][dcv * 5 + r5] += win[j + dcv] * ctr4[j];
      }
    }
    if (it < 30) asm volatile("s_waitcnt vmcnt(4)" ::: "memory");
    else         asm volatile("s_waitcnt vmcnt(0)" ::: "memory");
    __builtin_amdgcn_sched_barrier(0);
    __builtin_amdgcn_s_barrier();
  }

  int p0 = b * 4096 + (h0 + hr) * 64 + w0;
#pragma unroll
  for (int jj = 0; jj < 25; ++jj) {
    f32x4 v = {acc[0][jj], acc[1][jj], acc[2][jj], acc[3][jj]};
    *reinterpret_cast<f32x4*>(&part[(size_t)(chunk * 25 + jj) * NPIX + p0]) = v;
  }
}

// ---------------------------------------------------------------------------
// K4: reduce 16 chunks, scale by inv[p]*inv[p+d], write x cols 1024..1055
// ---------------------------------------------------------------------------
__global__ __launch_bounds__(256) void corr_reduce(const float* __restrict__ part,
                                                   const float* __restrict__ inv_norm,
                                                   unsigned short* __restrict__ xb) {
  int pl = blockIdx.x * 256 + threadIdx.x;
  int w = pl & 63, h = (pl >> 6) & 63, b = pl >> 12;
  float inv_c = inv_norm[pl];
  float vals[32];
#pragma unroll
  for (int j = 0; j < 32; ++j) {
    float v = 0.0f;
    if (j < 25) {
      int dc = j / 5 - 2, dr = j % 5 - 2;
      int hh = h + dr, ww = w + dc;
      if (hh >= 0 && hh < 64 && ww >= 0 && ww < 64) {
        float s = 0.0f;
#pragma unroll
        for (int c = 0; c < NCHUNK; ++c)
          s += part[(size_t)(c * 25 + j) * NPIX + pl];
        v = s * inv_c * inv_norm[(b << 12) + (hh << 6) + ww];
      }
    }
    vals[j] = v;
  }
  unsigned short* xp = xb + (size_t)pl * KPAD + 1024;
#pragma unroll
  for (int g = 0; g < 4; ++g) {
    u16x8 pk;
#pragma unroll
    for (int e = 0; e < 8; ++e) pk[e] = f2bf(vals[g * 8 + e]);
    *reinterpret_cast<u16x8*>(xp + g * 8) = pk;
  }
}

// ---------------------------------------------------------------------------
// K5: GEMM, 2-phase double-buffered K-loop (round-8 validated body, 117us)
//     + __launch_bounds__(256,4) to raise resident blocks/CU (VGPR 64 fits).
// ---------------------------------------------------------------------------
__device__ __forceinline__ void stage_tile(const unsigned short* __restrict__ g,
                                           unsigned short* s, int t) {
#pragma unroll
  for (int r = 0; r < 2; ++r) {
    int idx = t + r * 256;
    int row = idx >> 2;
    int q = (idx & 3) ^ ((row >> 1) & 3);
    const unsigned short* gp = g + (size_t)row * KPAD + q * 8;
    unsigned short* sp = s + (t >> 6) * 512 + r * 2048;
    __builtin_amdgcn_global_load_lds((gas_t)gp, (las_t)sp, 16, 0, 0);
  }
}

__global__ __launch_bounds__(256, 4) void gemm_kernel(
    const unsigned short* __restrict__ xb, const unsigned short* __restrict__ wb,
    const float* __restrict__ bias, float* __restrict__ out,
    int p_base, int np) {
  __shared__ __align__(16) unsigned short sA[2][4096];
  __shared__ __align__(16) unsigned short sB[2][4096];
  int t = threadIdx.x;
  int lane = t & 63;
  int wid = t >> 6;
  int wm = wid >> 1, wn = wid & 1;
  int l15 = lane & 15, l4 = lane >> 4;
  int bid = blockIdx.x;
  int xcd = bid & 7;
  int j = bid >> 3;
  int o0 = (j & 7) * 128;
  int panel = xcd * (np >> 3) + (j >> 3);
  int p0l = panel * 128;

  f32x4 acc[4][4];
#pragma unroll
  for (int m = 0; m < 4; ++m)
#pragma unroll
    for (int n = 0; n < 4; ++n)
#pragma unroll
      for (int i = 0; i < 4; ++i) acc[m][n][i] = 0.0f;

  const unsigned short* A = wb + (size_t)o0 * KPAD;
  const unsigned short* B = xb + (size_t)p0l * KPAD;

  stage_tile(A, sA[0], t);
  stage_tile(B, sB[0], t);
  __syncthreads();

  int cur = 0;
  const int NKT = KPAD / 32;   // 33
  for (int kt = 0; kt < NKT; ++kt) {
    if (kt + 1 < NKT) {
      stage_tile(A + (kt + 1) * 32, sA[cur ^ 1], t);
      stage_tile(B + (kt + 1) * 32, sB[cur ^ 1], t);
    }
    bf16x8 bf[4];
#pragma unroll
    for (int n = 0; n < 4; ++n) {
      int rr = wn * 64 + n * 16 + l15;
      int off = rr * 32 + ((l4 ^ ((rr >> 1) & 3)) * 8);
      bf[n] = *reinterpret_cast<const bf16x8*>(&sB[cur][off]);
    }
#pragma unroll
    for (int m = 0; m < 4; ++m) {
      int ra = wm * 64 + m * 16 + l15;
      int off = ra * 32 + ((l4 ^ ((ra >> 1) & 3)) * 8);
      bf16x8 af = *reinterpret_cast<const bf16x8*>(&sA[cur][off]);
#pragma unroll
      for (int n = 0; n < 4; ++n)
        acc[m][n] = __builtin_amdgcn_mfma_f32_16x16x32_bf16(af, bf[n], acc[m][n], 0, 0, 0);
    }
    __syncthreads();   // my reads of cur done + next tile landed
    cur ^= 1;
  }

#pragma unroll
  for (int m = 0; m < 4; ++m) {
    int ob = o0 + wm * 64 + m * 16 + l4 * 4;
    float b0 = bias[ob], b1 = bias[ob + 1], b2 = bias[ob + 2], b3 = bias[ob + 3];
#pragma unroll
    for (int n = 0; n < 4; ++n) {
      int pg = p_base + p0l + wn * 64 + n * 16 + l15;
      int bb = pg >> 12, hw = pg & 4095;
      float* op = out + ((size_t)bb << 22) + hw;
      op[(size_t)(ob + 0) << 12] = fmaxf(acc[m][n][0] + b0, 0.0f);
      op[(size_t)(ob + 1) << 12] = fmaxf(acc[m][n][1] + b1, 0.0f);
      op[(size_t)(ob + 2) << 12] = fmaxf(acc[m][n][2] + b2, 0.0f);
      op[(size_t)(ob + 3) << 12] = fmaxf(acc[m][n][3] + b3, 0.0f);
    }
  }
}

// ---------------------------------------------------------------------------
extern "C" void kernel_launch(void* const* d_in, const int* in_sizes, int n_in,
                              void* d_out, int out_size, void* d_ws, size_t ws_size,
                              hipStream_t stream) {
  const float* feat = (const float*)d_in[0];
  const float* cw   = (const float*)d_in[1];
  const float* cb   = (const float*)d_in[2];
  float* out = (float*)d_out;

  // single pass: xb 69.2MB + wb 2.2MB + inv 0.13MB + part 52.4MB = 124MB < 512MiB
  char* ws = (char*)d_ws;
  size_t SZ_X = (size_t)NPIX * KPAD * 2;
  size_t SZ_W = (size_t)1024 * KPAD * 2;
  unsigned short* xb = (unsigned short*)(ws);
  unsigned short* wb = (unsigned short*)(ws + SZ_X);
  float* inv_norm    = (float*)(ws + SZ_X + SZ_W);
  float* part        = (float*)(ws + SZ_X + SZ_W + (size_t)NPIX * 4);

  prep_w<<<1024, 256, 0, stream>>>(cw, wb);
  pack_norm<<<512, 256, 0, stream>>>(feat, xb, inv_norm, 0);
  corr_part<<<512, 256, 0, stream>>>(feat, part);
  corr_reduce<<<128, 256, 0, stream>>>(part, inv_norm, xb);
  gemm_kernel<<<2048, 256, 0, stream>>>(xb, wb, cb, out, 0, 256);
}